// Round 13
// baseline (341.691 us; speedup 1.0000x reference)
//
#include <hip/hip_runtime.h>
#include <hip/hip_bf16.h>

typedef __attribute__((ext_vector_type(8))) short s16x8;
typedef __attribute__((ext_vector_type(4))) float f32x4;

#define HC 48        // edge chunks (hist + scatter)
#define RBH 12800    // hist bins per range, packed 2-per-u32 (25.6 KB, 8 ranges)
#define RBS 6400     // scatter cursors per range (25.6 KB, 16 ranges)

static __device__ __forceinline__ unsigned short f2bf(float f) {
    unsigned int u = __float_as_uint(f);
    unsigned int r = (u + 0x7FFFu + ((u >> 16) & 1u)) >> 16;
    return (unsigned short)r;
}

// ---- partial histograms, u16 bins packed 2-per-u32 (verified R12) ----
__global__ __launch_bounds__(256) void k_hist(const int* __restrict__ eidx,
                                              unsigned short* __restrict__ partials,
                                              int N, int E, int HR) {
    __shared__ unsigned int h[RBH / 2];
    int b = blockIdx.x;
    int job = b / (HR * HC);
    int rc = b % (HR * HC);
    int r = rc / HC, c = rc % HC;
    int lo = r * RBH;
    int nb = min(RBH, N - lo);
    if (nb <= 0) return;
    int nw = (nb + 1) >> 1;
    for (int i = threadIdx.x; i < nw; i += 256) h[i] = 0;
    __syncthreads();
    const int* vals = eidx + (size_t)job * E;
    int e0 = (int)(((long long)E * c / HC) & ~3LL);
    int e1 = (c == HC - 1) ? E : (int)(((long long)E * (c + 1) / HC) & ~3LL);
    int e = e0 + threadIdx.x * 4;
    for (; e + 4 <= e1; e += 1024) {
        int4 v = *reinterpret_cast<const int4*>(vals + e);
        unsigned r0 = (unsigned)(v.x - lo), r1 = (unsigned)(v.y - lo);
        unsigned r2 = (unsigned)(v.z - lo), r3 = (unsigned)(v.w - lo);
        if (r0 < (unsigned)nb) atomicAdd(&h[r0 >> 1], 1u << ((r0 & 1) << 4));
        if (r1 < (unsigned)nb) atomicAdd(&h[r1 >> 1], 1u << ((r1 & 1) << 4));
        if (r2 < (unsigned)nb) atomicAdd(&h[r2 >> 1], 1u << ((r2 & 1) << 4));
        if (r3 < (unsigned)nb) atomicAdd(&h[r3 >> 1], 1u << ((r3 & 1) << 4));
    }
    if (threadIdx.x == 0)
        for (int t = e1 & ~3; t < e1; ++t) {
            unsigned rel = (unsigned)(vals[t] - lo);
            if (rel < (unsigned)nb) atomicAdd(&h[rel >> 1], 1u << ((rel & 1) << 4));
        }
    __syncthreads();
    unsigned short* outp = partials + ((size_t)(job * HC + c)) * N + lo;
    for (int i = threadIdx.x; i < nb; i += 256)
        outp[i] = (unsigned short)((h[i >> 1] >> ((i & 1) << 4)) & 0xffffu);
}

// ---- fused: partials -> dis/dsi/cnt + block scan + degree histogram ----
__global__ __launch_bounds__(1024) void k_rs(const unsigned short* __restrict__ partials,
                                             float* __restrict__ dis,
                                             float* __restrict__ dsi,
                                             int* __restrict__ cnt,
                                             int* __restrict__ incl,
                                             int* __restrict__ bsum,
                                             int* __restrict__ gdh, int N) {
    __shared__ int sm[1024];
    __shared__ int dh[64];
    int t = threadIdx.x;
    int i = blockIdx.x * 1024 + t;
    if (t < 64) dh[t] = 0;
    int csum = 0;
    if (i < N) {
        int dsum = 0;
        for (int c = 0; c < HC; ++c) {
            dsum += partials[(size_t)c * N + i];
            csum += partials[(size_t)(HC + c) * N + i];
        }
        dis[i] = dsum > 0 ? rsqrtf((float)dsum) : 0.f;
        dsi[i] = dsum > 0 ? sqrtf((float)dsum) : 0.f;
        cnt[i] = csum;
    }
    sm[t] = (i < N) ? csum : 0;
    __syncthreads();
    if (i < N) atomicAdd(&dh[min(csum, 63)], 1);
    for (int off = 1; off < 1024; off <<= 1) {
        int add = (t >= off) ? sm[t - off] : 0;
        __syncthreads();
        sm[t] += add;
        __syncthreads();
    }
    if (i < N) incl[i] = sm[t];
    if (t == 1023) bsum[blockIdx.x] = sm[1023];
    if (t < 64 && dh[t] > 0) atomicAdd(&gdh[t], dh[t]);
}

// ---- scan finalize + per-chunk cursor bases + 64-bin degree-base scan ----
__global__ __launch_bounds__(1024) void k_scan3(const int* __restrict__ cnt,
                                                const int* __restrict__ bsum,
                                                int* __restrict__ rowptr,
                                                const unsigned short* __restrict__ pdst,
                                                int* __restrict__ cbase,
                                                const int* __restrict__ gdh,
                                                int* __restrict__ gcur, int N, int nb) {
    __shared__ int sb[128];
    int t = threadIdx.x;
    if (t < 128) sb[t] = (t < nb) ? bsum[t] : 0;
    __syncthreads();
    for (int off = 1; off < 128; off <<= 1) {
        int add = (t < 128 && t >= off) ? sb[t - off] : 0;
        __syncthreads();
        if (t < 128) sb[t] += add;
        __syncthreads();
    }
    if (blockIdx.x == 0 && t == 0) {        // exclusive scan of degree hist
        int run = 0;
        for (int b2 = 0; b2 < 64; ++b2) { gcur[b2] = run; run += gdh[b2]; }
    }
    int b = blockIdx.x;
    int boff = (b == 0) ? 0 : sb[b - 1];
    int total = sb[nb - 1];
    int i = b * 1024 + t;
    if (i >= N) return;
    int ex = rowptr[i] - cnt[i] + boff;
    rowptr[i] = ex;
    if (i == N - 1) rowptr[N] = total;
    int run = ex;
    for (int c = 0; c < HC; ++c) {
        size_t idx = (size_t)c * N + i;
        cbase[idx] = run;
        run += pdst[idx];
    }
}

// ---- build degree-sorted node permutation (two-level counting sort):
// per-block LDS hist -> one global atomic claim per (bin,block) -> LDS rank.
// Any block/bin order yields a valid permutation; per-node math in prop is
// order-independent (edge order within a row is unchanged). ----
__global__ __launch_bounds__(1024) void k_perm(const int* __restrict__ cnt,
                                               int* __restrict__ gcur,
                                               int* __restrict__ perm, int N) {
    __shared__ int lh[64];
    __shared__ int lbase[64];
    __shared__ int lcur[64];
    int t = threadIdx.x;
    int i = blockIdx.x * 1024 + t;
    if (t < 64) { lh[t] = 0; lcur[t] = 0; }
    __syncthreads();
    int bin = 0;
    if (i < N) {
        bin = min(cnt[i], 63);
        atomicAdd(&lh[bin], 1);
    }
    __syncthreads();
    if (t < 64 && lh[t] > 0) lbase[t] = atomicAdd(&gcur[t], lh[t]);
    __syncthreads();
    if (i < N) {
        int r = atomicAdd(&lcur[bin], 1);
        perm[lbase[bin] + r] = i;
    }
}

// ---- merged scatter + pack (verified R12) ----
__global__ __launch_bounds__(256) void k_scpk(
        const int* __restrict__ src, const int* __restrict__ dst,
        const int* __restrict__ cbase, int* __restrict__ srcs, int N, int E, int SB,
        const float* __restrict__ x, const float* __restrict__ dis,
        const float* __restrict__ W,
        unsigned short* __restrict__ ysb, unsigned short* __restrict__ wt,
        float* __restrict__ walt, int K, int PSE) {
    __shared__ int cur[RBS];
    if ((int)blockIdx.x < SB) {
        int r = blockIdx.x / HC, c = blockIdx.x % HC;
        int lo = r * RBS;
        int nb = min(RBS, N - lo);
        if (nb <= 0) return;
        for (int i = threadIdx.x; i < nb; i += 256)
            cur[i] = cbase[(size_t)c * N + lo + i];
        __syncthreads();
        int e0 = (int)(((long long)E * c / HC) & ~3LL);
        int e1 = (c == HC - 1) ? E : (int)(((long long)E * (c + 1) / HC) & ~3LL);
        int e = e0 + threadIdx.x * 4;
        for (; e + 4 <= e1; e += 1024) {
            int4 d4 = *reinterpret_cast<const int4*>(dst + e);
            unsigned r0 = (unsigned)(d4.x - lo), r1 = (unsigned)(d4.y - lo);
            unsigned r2 = (unsigned)(d4.z - lo), r3 = (unsigned)(d4.w - lo);
            if (r0 < (unsigned)nb) srcs[atomicAdd(&cur[r0], 1)] = src[e];
            if (r1 < (unsigned)nb) srcs[atomicAdd(&cur[r1], 1)] = src[e + 1];
            if (r2 < (unsigned)nb) srcs[atomicAdd(&cur[r2], 1)] = src[e + 2];
            if (r3 < (unsigned)nb) srcs[atomicAdd(&cur[r3], 1)] = src[e + 3];
        }
        if (threadIdx.x == 0)
            for (int t = e1 & ~3; t < e1; ++t) {
                unsigned rel = (unsigned)(dst[t] - lo);
                if (rel < (unsigned)nb) srcs[atomicAdd(&cur[rel], 1)] = src[t];
            }
    } else {
        int t = (blockIdx.x - SB) * 256 + threadIdx.x;
        int nys = (N + 1) * 32;
        if (t < nys) {
            int row = t >> 5, p = t & 31;
            if (row == N) {
                for (int k = 0; k < K; ++k)
                    *(unsigned*)(ysb + (size_t)k * PSE + ((size_t)N << 6) + (p << 1)) = 0;
                return;
            }
            size_t o = ((size_t)row << 6) + (p << 1);
            float2 v = *reinterpret_cast<const float2*>(x + o);
            float dv = dis[row];
            *(unsigned*)(ysb + o) = (unsigned)f2bf(v.x * dv) | ((unsigned)f2bf(v.y * dv) << 16);
        } else {
            int u = t - nys;
            if (u < K * 4096) {
                float v = W[u];
                int k = u >> 12;
                int r = u & 4095;
                int i = r >> 6;
                int j = r & 63;
                wt[(size_t)j * (K * 64) + (k << 6) + i] = f2bf(v);
            } else if (u < K * 4096 + 4096) {
                int u2 = u - K * 4096;
                float s = 0.f;
                for (int k = 0; k < K; k += 2)
                    s += ((k & 3) == 0 ? 1.f : -1.f) * W[k * 4096 + u2];
                walt[u2] = s;
            }
        }
    }
}

static __device__ __forceinline__ void addrow(float* acc, uint4 t) {
    acc[0] += __uint_as_float(t.x << 16);
    acc[1] += __uint_as_float(t.x & 0xffff0000u);
    acc[2] += __uint_as_float(t.y << 16);
    acc[3] += __uint_as_float(t.y & 0xffff0000u);
    acc[4] += __uint_as_float(t.z << 16);
    acc[5] += __uint_as_float(t.z & 0xffff0000u);
    acc[6] += __uint_as_float(t.w << 16);
    acc[7] += __uint_as_float(t.w & 0xffff0000u);
}

// ---- Chebyshev propagation (R8/R11 math, degree-sorted node order):
// wave processes perm[wv*8 .. wv*8+7] — similar degrees, so the wmax tail
// waste (~35-40% of gather octets on Poisson degrees) vanishes. Per-node
// arithmetic is bit-identical to the unsorted version. ----
__global__ __launch_bounds__(256) void k_prop(
        const unsigned short* __restrict__ Ysin,
        const unsigned short* __restrict__ Ysm2,
        unsigned short* __restrict__ Ysout,
        const int* __restrict__ rowptr, const int* __restrict__ srcs,
        const float* __restrict__ dis, const int* __restrict__ perm,
        int N, int E, float scale, float beta) {
    int gt = blockIdx.x * blockDim.x + threadIdx.x;
    int wave0 = (gt >> 6) << 3;          // first perm slot of this wave
    int lane = gt & 63;
    int g = lane >> 3;                   // slot index
    int i = lane & 7;                    // feature octet
    int pidx = wave0 + g;
    bool live = pidx < N;
    int node = 0, rs = 0, deg = 0;
    if (live) {
        node = perm[pidx];
        rs = rowptr[node];
        deg = rowptr[node + 1] - rs;
    }
    int wmax = deg;
#pragma unroll
    for (int m = 8; m <= 32; m <<= 1) {
        int o = __shfl_xor(wmax, m);
        wmax = o > wmax ? o : wmax;
    }
    float acc[8];
#pragma unroll
    for (int j = 0; j < 8; ++j) acc[j] = 0.f;
    for (int e = 0; e < wmax; e += 8) {
        int b = rs + e;
        int s[8];
#pragma unroll
        for (int q = 0; q < 8; ++q)
            s[q] = (e + q < deg) ? srcs[min(b + q, E - 1)] : N;
        uint4 t[8];
#pragma unroll
        for (int q = 0; q < 8; ++q)
            t[q] = *reinterpret_cast<const uint4*>(Ysin + ((size_t)s[q] << 6) + (i << 3));
#pragma unroll
        for (int q = 0; q < 8; ++q) addrow(acc, t[q]);
    }
    if (live) {
        float dv = dis[node];
        float sc = -scale * dv * dv;
        size_t base = ((size_t)node << 6) + (i << 3);
        float r[8];
#pragma unroll
        for (int j = 0; j < 8; ++j) r[j] = sc * acc[j];
        if (beta != 0.f) {
            uint4 pv = *reinterpret_cast<const uint4*>(Ysm2 + base);
            r[0] = fmaf(beta, __uint_as_float(pv.x << 16), r[0]);
            r[1] = fmaf(beta, __uint_as_float(pv.x & 0xffff0000u), r[1]);
            r[2] = fmaf(beta, __uint_as_float(pv.y << 16), r[2]);
            r[3] = fmaf(beta, __uint_as_float(pv.y & 0xffff0000u), r[3]);
            r[4] = fmaf(beta, __uint_as_float(pv.z << 16), r[4]);
            r[5] = fmaf(beta, __uint_as_float(pv.z & 0xffff0000u), r[5]);
            r[6] = fmaf(beta, __uint_as_float(pv.w << 16), r[6]);
            r[7] = fmaf(beta, __uint_as_float(pv.w & 0xffff0000u), r[7]);
        }
        uint4 ov;
        ov.x = (unsigned)f2bf(r[0]) | ((unsigned)f2bf(r[1]) << 16);
        ov.y = (unsigned)f2bf(r[2]) | ((unsigned)f2bf(r[3]) << 16);
        ov.z = (unsigned)f2bf(r[4]) | ((unsigned)f2bf(r[5]) << 16);
        ov.w = (unsigned)f2bf(r[6]) | ((unsigned)f2bf(r[7]) << 16);
        *reinterpret_cast<uint4*>(Ysout + base) = ov;
    }
}

// ---- out = relu( dsi[n] * sum_k Ys_k @ W_k + bias ) (verified R11) ----
template <int KS>
__global__ __launch_bounds__(256) void k_gemm(const unsigned short* __restrict__ tb,
                                              const unsigned short* __restrict__ wt,
                                              const float* __restrict__ bias,
                                              const float* __restrict__ dsi,
                                              const float* __restrict__ x,
                                              const float* __restrict__ walt,
                                              float* __restrict__ out,
                                              int N, int PSE) {
    constexpr int NB = KS / 2;
    __shared__ unsigned short lds_b[KS * 512];
    __shared__ unsigned short lds_a[KS * 256 * 8];
    int tid = threadIdx.x;
    int lane = tid & 63;
    int w = tid >> 6;
    int l16 = lane & 15;
    int quad = lane >> 4;
    const int KI = KS * 32;

    {
        const unsigned short* wrow = wt + (size_t)(w * 16 + l16) * KI + quad * 8;
#pragma unroll
        for (int ks = 0; ks < KS; ++ks) {
            s16x8 v = *reinterpret_cast<const s16x8*>(wrow + ks * 32);
            *reinterpret_cast<s16x8*>(lds_a + (ks * 256 + tid) * 8) = v;
        }
    }
    f32x4 bias4 = *reinterpret_cast<const f32x4*>(bias + w * 16 + quad * 4);

    int ntiles = N >> 4;
    for (int t = blockIdx.x; t < ntiles; t += gridDim.x) {
        const char* tilebase = (const char*)tb + (size_t)t * 2048;
#pragma unroll
        for (int inst = 0; inst < 2 * NB; ++inst) {
            if ((inst & 3) != w) continue;
            int kbuf = inst >> 1;
            int j = inst & 1;
            int p = j * 64 + lane;
            int nrow = p >> 3;
            int s = (p & 7) ^ (nrow & 7);
            const char* g = tilebase + (size_t)kbuf * PSE * 2 + nrow * 128 + s * 16;
            __builtin_amdgcn_global_load_lds(
                (const __attribute__((address_space(1))) unsigned int*)g,
                (__attribute__((address_space(3))) unsigned int*)(lds_b + inst * 512),
                16, 0, 0);
        }
        __syncthreads();
        f32x4 acc = {0.f, 0.f, 0.f, 0.f};
#pragma unroll
        for (int ks = 0; ks < KS; ++ks) {
            s16x8 af = *reinterpret_cast<const s16x8*>(lds_a + (ks * 256 + tid) * 8);
            int kbuf = ks >> 1, half = ks & 1;
            int sph = (half * 4 + quad) ^ (l16 & 7);
            s16x8 bf = *reinterpret_cast<const s16x8*>(
                lds_b + kbuf * 1024 + l16 * 64 + sph * 8);
            acc = __builtin_amdgcn_mfma_f32_16x16x32_bf16(af, bf, acc, 0, 0, 0);
        }
        int row = t * 16 + l16;
        float dvi = dsi[row];
        float* orow = out + (size_t)row * 64 + w * 16 + quad * 4;
        f32x4 r;
        if (dvi != 0.f) {
#pragma unroll
            for (int q = 0; q < 4; ++q) {
                float v = fmaf(acc[q], dvi, bias4[q]);
                r[q] = v > 0.f ? v : 0.f;
            }
        } else {
            const float* xr = x + (size_t)row * 64;
            float rr[4] = {bias4[0], bias4[1], bias4[2], bias4[3]};
            for (int j = 0; j < 64; ++j) {
                float xv = xr[j];
                const float* wr = walt + j * 64 + w * 16 + quad * 4;
#pragma unroll
                for (int q = 0; q < 4; ++q) rr[q] = fmaf(xv, wr[q], rr[q]);
            }
#pragma unroll
            for (int q = 0; q < 4; ++q) r[q] = rr[q] > 0.f ? rr[q] : 0.f;
        }
        *reinterpret_cast<f32x4*>(orow) = r;
        __syncthreads();
    }
}

extern "C" void kernel_launch(void* const* d_in, const int* in_sizes, int n_in,
                              void* d_out, int out_size, void* d_ws, size_t ws_size,
                              hipStream_t stream) {
    const float* x    = (const float*)d_in[0];
    const int*   eidx = (const int*)d_in[1];
    const float* W    = (const float*)d_in[2];
    const float* bias = (const float*)d_in[3];
    float* out = (float*)d_out;

    const int NF = in_sizes[0];       // N*64
    const int N  = NF / 64;
    const int E  = in_sizes[1] / 2;
    const int K  = in_sizes[2] / 4096;

    const int* src = eidx;
    const int* dst = eidx + E;

    const int PSE = (N + 1) * 64;     // elems per Ys plane (row N = zero pad)

    char* ws = (char*)d_ws;
    size_t off = 0;
    auto alloc = [&](size_t bytes) -> char* {
        char* p = ws + off;
        off = (off + bytes + 255) & ~(size_t)255;
        return p;
    };
    unsigned short* Ysb = (unsigned short*)alloc((size_t)K * PSE * 2);
    unsigned short* Wt = (unsigned short*)alloc((size_t)64 * K * 64 * 2);
    float* Walt  = (float*)alloc(4096 * 4);
    int*   srcs   = (int*)alloc((size_t)E * 4);
    int*   rowptr = (int*)alloc((size_t)(N + 1) * 4);
    int*   cnt    = (int*)alloc((size_t)N * 4);
    int*   perm   = (int*)alloc((size_t)N * 4);
    unsigned short* partials = (unsigned short*)alloc((size_t)2 * HC * N * 2);
    int*   cbase  = (int*)alloc((size_t)HC * N * 4);
    float* dis  = (float*)alloc((size_t)N * 4);
    float* dsi  = (float*)alloc((size_t)N * 4);
    int*   bsum = (int*)alloc(1024);
    int*   gdh  = (int*)alloc(256);
    int*   gcur = (int*)alloc(256);
    (void)ws_size; (void)n_in; (void)out_size;

    int HR = (N + RBH - 1) / RBH;   // 8
    int SR = (N + RBS - 1) / RBS;   // 16
    const unsigned short* pdst = partials + (size_t)HC * N;

    hipMemsetAsync(gdh, 0, 256, stream);
    k_hist<<<2 * HR * HC, 256, 0, stream>>>(eidx, partials, N, E, HR);
    int nb = (N + 1023) / 1024;
    k_rs<<<nb, 1024, 0, stream>>>(partials, dis, dsi, cnt, rowptr, bsum, gdh, N);
    k_scan3<<<nb, 1024, 0, stream>>>(cnt, bsum, rowptr, pdst, cbase, gdh, gcur, N, nb);
    k_perm<<<nb, 1024, 0, stream>>>(cnt, gcur, perm, N);

    int SB = SR * HC;
    int packn = (N + 1) * 32 + K * 4096 + 4096;
    int pblk = (packn + 255) / 256;
    k_scpk<<<SB + pblk, 256, 0, stream>>>(src, dst, cbase, srcs, N, E, SB,
                                          x, dis, W, Ysb, Wt, Walt, K, PSE);

    // prop grid: 8 nodes per wave (degree-sorted via perm)
    int waves = (N + 7) / 8;
    int pblocks = (waves * 64 + 255) / 256;
    for (int p = 1; p < K; ++p) {
        float scale = (p == 1) ? 1.f : 2.f;
        float beta  = (p == 1) ? 0.f : -1.f;
        const unsigned short* Ysin = Ysb + (size_t)(p - 1) * PSE;
        const unsigned short* Ysm2 = Ysb + (size_t)(p >= 2 ? p - 2 : 0) * PSE;
        k_prop<<<pblocks, 256, 0, stream>>>(
            Ysin, Ysm2, Ysb + (size_t)p * PSE,
            rowptr, srcs, dis, perm, N, E, scale, beta);
    }

    if (K == 8)      k_gemm<16><<<512, 256, 0, stream>>>(Ysb, Wt, bias, dsi, x, Walt, out, N, PSE);
    else if (K == 4) k_gemm<8><<<512, 256, 0, stream>>>(Ysb, Wt, bias, dsi, x, Walt, out, N, PSE);
    else if (K == 2) k_gemm<4><<<512, 256, 0, stream>>>(Ysb, Wt, bias, dsi, x, Walt, out, N, PSE);
    else if (K == 1) k_gemm<2><<<512, 256, 0, stream>>>(Ysb, Wt, bias, dsi, x, Walt, out, N, PSE);
}

// Round 14
// 317.262 us; speedup vs baseline: 1.0770x; 1.0770x over previous
//
#include <hip/hip_runtime.h>
#include <hip/hip_bf16.h>

typedef __attribute__((ext_vector_type(8))) short s16x8;
typedef __attribute__((ext_vector_type(4))) float f32x4;

#define HC 48        // edge chunks (hist + scatter)
#define RBH 12800    // hist bins per range, packed 2-per-u32 (25.6 KB, 8 ranges)
#define RBS 6400     // scatter cursors per range (25.6 KB, 16 ranges)

static __device__ __forceinline__ unsigned short f2bf(float f) {
    unsigned int u = __float_as_uint(f);
    unsigned int r = (u + 0x7FFFu + ((u >> 16) & 1u)) >> 16;
    return (unsigned short)r;
}

// ---- partial histograms, u16 bins packed 2-per-u32 (per-chunk count <= E/HC
// = 20.9k < 65536, so low half can never carry into high). Same 25.6 KB LDS
// (6 blocks/CU) as the verified 6400-int version but HALF the ranges -> edge
// re-reads 128 -> 64 MB. ----
__global__ __launch_bounds__(256) void k_hist(const int* __restrict__ eidx,
                                              unsigned short* __restrict__ partials,
                                              int N, int E, int HR) {
    __shared__ unsigned int h[RBH / 2];
    int b = blockIdx.x;
    int job = b / (HR * HC);
    int rc = b % (HR * HC);
    int r = rc / HC, c = rc % HC;
    int lo = r * RBH;
    int nb = min(RBH, N - lo);
    if (nb <= 0) return;
    int nw = (nb + 1) >> 1;
    for (int i = threadIdx.x; i < nw; i += 256) h[i] = 0;
    __syncthreads();
    const int* vals = eidx + (size_t)job * E;
    int e0 = (int)(((long long)E * c / HC) & ~3LL);
    int e1 = (c == HC - 1) ? E : (int)(((long long)E * (c + 1) / HC) & ~3LL);
    int e = e0 + threadIdx.x * 4;
    for (; e + 4 <= e1; e += 1024) {
        int4 v = *reinterpret_cast<const int4*>(vals + e);
        unsigned r0 = (unsigned)(v.x - lo), r1 = (unsigned)(v.y - lo);
        unsigned r2 = (unsigned)(v.z - lo), r3 = (unsigned)(v.w - lo);
        if (r0 < (unsigned)nb) atomicAdd(&h[r0 >> 1], 1u << ((r0 & 1) << 4));
        if (r1 < (unsigned)nb) atomicAdd(&h[r1 >> 1], 1u << ((r1 & 1) << 4));
        if (r2 < (unsigned)nb) atomicAdd(&h[r2 >> 1], 1u << ((r2 & 1) << 4));
        if (r3 < (unsigned)nb) atomicAdd(&h[r3 >> 1], 1u << ((r3 & 1) << 4));
    }
    if (threadIdx.x == 0)
        for (int t = e1 & ~3; t < e1; ++t) {
            unsigned rel = (unsigned)(vals[t] - lo);
            if (rel < (unsigned)nb) atomicAdd(&h[rel >> 1], 1u << ((rel & 1) << 4));
        }
    __syncthreads();
    unsigned short* outp = partials + ((size_t)(job * HC + c)) * N + lo;
    for (int i = threadIdx.x; i < nb; i += 256)
        outp[i] = (unsigned short)((h[i >> 1] >> ((i & 1) << 4)) & 0xffffu);
}

// ---- fused: combine partials -> dis (rsqrt), dsi (sqrt), cnt; block scan ----
__global__ __launch_bounds__(1024) void k_rs(const unsigned short* __restrict__ partials,
                                             float* __restrict__ dis,
                                             float* __restrict__ dsi,
                                             int* __restrict__ cnt,
                                             int* __restrict__ incl,
                                             int* __restrict__ bsum, int N) {
    __shared__ int sm[1024];
    int t = threadIdx.x;
    int i = blockIdx.x * 1024 + t;
    int csum = 0;
    if (i < N) {
        int dsum = 0;
        for (int c = 0; c < HC; ++c) {
            dsum += partials[(size_t)c * N + i];
            csum += partials[(size_t)(HC + c) * N + i];
        }
        dis[i] = dsum > 0 ? rsqrtf((float)dsum) : 0.f;
        dsi[i] = dsum > 0 ? sqrtf((float)dsum) : 0.f;
        cnt[i] = csum;
    }
    sm[t] = (i < N) ? csum : 0;
    __syncthreads();
    for (int off = 1; off < 1024; off <<= 1) {
        int add = (t >= off) ? sm[t - off] : 0;
        __syncthreads();
        sm[t] += add;
        __syncthreads();
    }
    if (i < N) incl[i] = sm[t];
    if (t == 1023) bsum[blockIdx.x] = sm[1023];
}

// ---- scan finalize + per-chunk cursor bases (verified R5/R7 pattern) ----
__global__ __launch_bounds__(1024) void k_scan3(const int* __restrict__ cnt,
                                                const int* __restrict__ bsum,
                                                int* __restrict__ rowptr,
                                                const unsigned short* __restrict__ pdst,
                                                int* __restrict__ cbase, int N, int nb) {
    __shared__ int sb[128];
    int t = threadIdx.x;
    if (t < 128) sb[t] = (t < nb) ? bsum[t] : 0;
    __syncthreads();
    for (int off = 1; off < 128; off <<= 1) {
        int add = (t < 128 && t >= off) ? sb[t - off] : 0;
        __syncthreads();
        if (t < 128) sb[t] += add;
        __syncthreads();
    }
    int b = blockIdx.x;
    int boff = (b == 0) ? 0 : sb[b - 1];
    int total = sb[nb - 1];
    int i = b * 1024 + t;
    if (i >= N) return;
    int ex = rowptr[i] - cnt[i] + boff;
    rowptr[i] = ex;
    if (i == N - 1) rowptr[N] = total;
    int run = ex;
    for (int c = 0; c < HC; ++c) {
        size_t idx = (size_t)c * N + i;
        cbase[idx] = run;
        run += pdst[idx];
    }
}

// ---- merged scatter + pack (role-split by blockIdx; both depend only on
// rs/scan3 outputs, so one dispatch replaces two). Scatter: RBS 6400 ints =
// 25.6 KB (still 6 blocks/CU) -> 16 ranges -> dst re-reads 128 -> 64 MB. ----
__global__ __launch_bounds__(256) void k_scpk(
        const int* __restrict__ src, const int* __restrict__ dst,
        const int* __restrict__ cbase, int* __restrict__ srcs, int N, int E, int SB,
        const float* __restrict__ x, const float* __restrict__ dis,
        const float* __restrict__ W,
        unsigned short* __restrict__ ysb, unsigned short* __restrict__ wt,
        float* __restrict__ walt, int K, int PSE) {
    __shared__ int cur[RBS];
    if ((int)blockIdx.x < SB) {
        // ---------------- scatter role ----------------
        int r = blockIdx.x / HC, c = blockIdx.x % HC;
        int lo = r * RBS;
        int nb = min(RBS, N - lo);
        if (nb <= 0) return;
        for (int i = threadIdx.x; i < nb; i += 256)
            cur[i] = cbase[(size_t)c * N + lo + i];
        __syncthreads();
        int e0 = (int)(((long long)E * c / HC) & ~3LL);
        int e1 = (c == HC - 1) ? E : (int)(((long long)E * (c + 1) / HC) & ~3LL);
        int e = e0 + threadIdx.x * 4;
        for (; e + 4 <= e1; e += 1024) {
            int4 d4 = *reinterpret_cast<const int4*>(dst + e);
            unsigned r0 = (unsigned)(d4.x - lo), r1 = (unsigned)(d4.y - lo);
            unsigned r2 = (unsigned)(d4.z - lo), r3 = (unsigned)(d4.w - lo);
            if (r0 < (unsigned)nb) srcs[atomicAdd(&cur[r0], 1)] = src[e];
            if (r1 < (unsigned)nb) srcs[atomicAdd(&cur[r1], 1)] = src[e + 1];
            if (r2 < (unsigned)nb) srcs[atomicAdd(&cur[r2], 1)] = src[e + 2];
            if (r3 < (unsigned)nb) srcs[atomicAdd(&cur[r3], 1)] = src[e + 3];
        }
        if (threadIdx.x == 0)
            for (int t = e1 & ~3; t < e1; ++t) {
                unsigned rel = (unsigned)(dst[t] - lo);
                if (rel < (unsigned)nb) srcs[atomicAdd(&cur[rel], 1)] = src[t];
            }
    } else {
        // ---------------- pack role ----------------
        int t = (blockIdx.x - SB) * 256 + threadIdx.x;
        int nys = (N + 1) * 32;
        if (t < nys) {
            int row = t >> 5, p = t & 31;
            if (row == N) {   // zero the pad row of every plane
                for (int k = 0; k < K; ++k)
                    *(unsigned*)(ysb + (size_t)k * PSE + ((size_t)N << 6) + (p << 1)) = 0;
                return;
            }
            size_t o = ((size_t)row << 6) + (p << 1);
            float2 v = *reinterpret_cast<const float2*>(x + o);
            float dv = dis[row];
            *(unsigned*)(ysb + o) = (unsigned)f2bf(v.x * dv) | ((unsigned)f2bf(v.y * dv) << 16);
        } else {
            int u = t - nys;
            if (u < K * 4096) {
                float v = W[u];
                int k = u >> 12;
                int r = u & 4095;
                int i = r >> 6;
                int j = r & 63;
                wt[(size_t)j * (K * 64) + (k << 6) + i] = f2bf(v);
            } else if (u < K * 4096 + 4096) {
                int u2 = u - K * 4096;          // u2 = j*64 + i
                float s = 0.f;
                for (int k = 0; k < K; k += 2)
                    s += ((k & 3) == 0 ? 1.f : -1.f) * W[k * 4096 + u2];
                walt[u2] = s;
            }
        }
    }
}

static __device__ __forceinline__ void addrow(float* acc, uint4 t) {
    acc[0] += __uint_as_float(t.x << 16);
    acc[1] += __uint_as_float(t.x & 0xffff0000u);
    acc[2] += __uint_as_float(t.y << 16);
    acc[3] += __uint_as_float(t.y & 0xffff0000u);
    acc[4] += __uint_as_float(t.z << 16);
    acc[5] += __uint_as_float(t.z & 0xffff0000u);
    acc[6] += __uint_as_float(t.w << 16);
    acc[7] += __uint_as_float(t.w & 0xffff0000u);
}

// ---- Chebyshev propagation in Ys-space: Ys_p = -scale*dis^2*acc + beta*Ys_{p-2}
// (exact R8/R10/R11-verified version; R13 showed contiguous node groups beat
// degree-sorted groups — locality of writes/srcs-ranges dominates tail waste)
__global__ __launch_bounds__(256) void k_prop(
        const unsigned short* __restrict__ Ysin,
        const unsigned short* __restrict__ Ysm2,
        unsigned short* __restrict__ Ysout,
        const int* __restrict__ rowptr, const int* __restrict__ srcs,
        const float* __restrict__ dis,
        int N, int E, float scale, float beta) {
    int gt = blockIdx.x * blockDim.x + threadIdx.x;
    int wave0 = (gt >> 6) << 3;          // first node of this wave
    int lane = gt & 63;
    int g = lane >> 3;                   // slot -> node wave0+g
    int i = lane & 7;                    // feature octet
    int node = wave0 + g;
    bool live = node < N;
    int rs = 0, deg = 0;
    if (live) {
        rs = rowptr[node];
        deg = rowptr[node + 1] - rs;
    }
    int wmax = deg;
#pragma unroll
    for (int m = 8; m <= 32; m <<= 1) {
        int o = __shfl_xor(wmax, m);
        wmax = o > wmax ? o : wmax;
    }
    float acc[8];
#pragma unroll
    for (int j = 0; j < 8; ++j) acc[j] = 0.f;
    for (int e = 0; e < wmax; e += 8) {
        int b = rs + e;
        int s[8];
#pragma unroll
        for (int q = 0; q < 8; ++q)
            s[q] = (e + q < deg) ? srcs[min(b + q, E - 1)] : N;
        uint4 t[8];
#pragma unroll
        for (int q = 0; q < 8; ++q)
            t[q] = *reinterpret_cast<const uint4*>(Ysin + ((size_t)s[q] << 6) + (i << 3));
#pragma unroll
        for (int q = 0; q < 8; ++q) addrow(acc, t[q]);
    }
    if (live) {
        float dv = dis[node];
        float sc = -scale * dv * dv;
        size_t base = ((size_t)node << 6) + (i << 3);
        float r[8];
#pragma unroll
        for (int j = 0; j < 8; ++j) r[j] = sc * acc[j];
        if (beta != 0.f) {
            uint4 pv = *reinterpret_cast<const uint4*>(Ysm2 + base);
            r[0] = fmaf(beta, __uint_as_float(pv.x << 16), r[0]);
            r[1] = fmaf(beta, __uint_as_float(pv.x & 0xffff0000u), r[1]);
            r[2] = fmaf(beta, __uint_as_float(pv.y << 16), r[2]);
            r[3] = fmaf(beta, __uint_as_float(pv.y & 0xffff0000u), r[3]);
            r[4] = fmaf(beta, __uint_as_float(pv.z << 16), r[4]);
            r[5] = fmaf(beta, __uint_as_float(pv.z & 0xffff0000u), r[5]);
            r[6] = fmaf(beta, __uint_as_float(pv.w << 16), r[6]);
            r[7] = fmaf(beta, __uint_as_float(pv.w & 0xffff0000u), r[7]);
        }
        uint4 ov;
        ov.x = (unsigned)f2bf(r[0]) | ((unsigned)f2bf(r[1]) << 16);
        ov.y = (unsigned)f2bf(r[2]) | ((unsigned)f2bf(r[3]) << 16);
        ov.z = (unsigned)f2bf(r[4]) | ((unsigned)f2bf(r[5]) << 16);
        ov.w = (unsigned)f2bf(r[6]) | ((unsigned)f2bf(r[7]) << 16);
        *reinterpret_cast<uint4*>(Ysout + base) = ov;
    }
}

// ---- out = relu( dsi[n] * sum_k Ys_k @ W_k + bias ); deg-0 rows use Walt ----
// (exact R11/R12-verified version: per-thread A-fragments in LDS)
template <int KS>
__global__ __launch_bounds__(256) void k_gemm(const unsigned short* __restrict__ tb,
                                              const unsigned short* __restrict__ wt,
                                              const float* __restrict__ bias,
                                              const float* __restrict__ dsi,
                                              const float* __restrict__ x,
                                              const float* __restrict__ walt,
                                              float* __restrict__ out,
                                              int N, int PSE) {
    constexpr int NB = KS / 2;                 // 64-wide k-buffers per tile
    __shared__ unsigned short lds_b[KS * 512]; // 16 KB B-tile (KS=16)
    __shared__ unsigned short lds_a[KS * 256 * 8]; // 64 KB per-thread A frags
    int tid = threadIdx.x;
    int lane = tid & 63;
    int w = tid >> 6;
    int l16 = lane & 15;
    int quad = lane >> 4;
    const int KI = KS * 32;

    {
        const unsigned short* wrow = wt + (size_t)(w * 16 + l16) * KI + quad * 8;
#pragma unroll
        for (int ks = 0; ks < KS; ++ks) {
            s16x8 v = *reinterpret_cast<const s16x8*>(wrow + ks * 32);
            *reinterpret_cast<s16x8*>(lds_a + (ks * 256 + tid) * 8) = v;
        }
    }
    f32x4 bias4 = *reinterpret_cast<const f32x4*>(bias + w * 16 + quad * 4);

    int ntiles = N >> 4;
    for (int t = blockIdx.x; t < ntiles; t += gridDim.x) {
        const char* tilebase = (const char*)tb + (size_t)t * 2048;  // 16 rows * 64 * 2B
#pragma unroll
        for (int inst = 0; inst < 2 * NB; ++inst) {
            if ((inst & 3) != w) continue;
            int kbuf = inst >> 1;
            int j = inst & 1;
            int p = j * 64 + lane;          // physical 16B slot within kbuf chunk
            int nrow = p >> 3;              // node 0..15
            int s = (p & 7) ^ (nrow & 7);   // logical seg for this physical slot
            const char* g = tilebase + (size_t)kbuf * PSE * 2 + nrow * 128 + s * 16;
            __builtin_amdgcn_global_load_lds(
                (const __attribute__((address_space(1))) unsigned int*)g,
                (__attribute__((address_space(3))) unsigned int*)(lds_b + inst * 512),
                16, 0, 0);
        }
        __syncthreads();   // drains vmcnt (incl. load_lds) + barrier
        f32x4 acc = {0.f, 0.f, 0.f, 0.f};
#pragma unroll
        for (int ks = 0; ks < KS; ++ks) {
            s16x8 af = *reinterpret_cast<const s16x8*>(lds_a + (ks * 256 + tid) * 8);
            int kbuf = ks >> 1, half = ks & 1;
            int sph = (half * 4 + quad) ^ (l16 & 7);
            s16x8 bf = *reinterpret_cast<const s16x8*>(
                lds_b + kbuf * 1024 + l16 * 64 + sph * 8);
            acc = __builtin_amdgcn_mfma_f32_16x16x32_bf16(af, bf, acc, 0, 0, 0);
        }
        int row = t * 16 + l16;
        float dvi = dsi[row];
        float* orow = out + (size_t)row * 64 + w * 16 + quad * 4;
        f32x4 r;
        if (dvi != 0.f) {
#pragma unroll
            for (int q = 0; q < 4; ++q) {
                float v = fmaf(acc[q], dvi, bias4[q]);
                r[q] = v > 0.f ? v : 0.f;
            }
        } else {
            const float* xr = x + (size_t)row * 64;
            float rr[4] = {bias4[0], bias4[1], bias4[2], bias4[3]};
            for (int j = 0; j < 64; ++j) {
                float xv = xr[j];
                const float* wr = walt + j * 64 + w * 16 + quad * 4;
#pragma unroll
                for (int q = 0; q < 4; ++q) rr[q] = fmaf(xv, wr[q], rr[q]);
            }
#pragma unroll
            for (int q = 0; q < 4; ++q) r[q] = rr[q] > 0.f ? rr[q] : 0.f;
        }
        *reinterpret_cast<f32x4*>(orow) = r;
        __syncthreads();
    }
}

extern "C" void kernel_launch(void* const* d_in, const int* in_sizes, int n_in,
                              void* d_out, int out_size, void* d_ws, size_t ws_size,
                              hipStream_t stream) {
    const float* x    = (const float*)d_in[0];
    const int*   eidx = (const int*)d_in[1];
    const float* W    = (const float*)d_in[2];
    const float* bias = (const float*)d_in[3];
    float* out = (float*)d_out;

    const int NF = in_sizes[0];       // N*64
    const int N  = NF / 64;
    const int E  = in_sizes[1] / 2;
    const int K  = in_sizes[2] / 4096;

    const int* src = eidx;
    const int* dst = eidx + E;

    const int PSE = (N + 1) * 64;     // elems per Ys plane (row N = zero pad)

    char* ws = (char*)d_ws;
    size_t off = 0;
    auto alloc = [&](size_t bytes) -> char* {
        char* p = ws + off;
        off = (off + bytes + 255) & ~(size_t)255;
        return p;
    };
    unsigned short* Ysb = (unsigned short*)alloc((size_t)K * PSE * 2);  // bf16 Ys_0..Ys_{K-1}
    unsigned short* Wt = (unsigned short*)alloc((size_t)64 * K * 64 * 2);
    float* Walt  = (float*)alloc(4096 * 4);
    int*   srcs   = (int*)alloc((size_t)E * 4);
    int*   rowptr = (int*)alloc((size_t)(N + 1) * 4);
    int*   cnt    = (int*)alloc((size_t)N * 4);
    unsigned short* partials = (unsigned short*)alloc((size_t)2 * HC * N * 2);
    int*   cbase  = (int*)alloc((size_t)HC * N * 4);
    float* dis  = (float*)alloc((size_t)N * 4);
    float* dsi  = (float*)alloc((size_t)N * 4);
    int*   bsum = (int*)alloc(1024);
    (void)ws_size; (void)n_in; (void)out_size;

    int HR = (N + RBH - 1) / RBH;   // 8
    int SR = (N + RBS - 1) / RBS;   // 16
    const unsigned short* pdst = partials + (size_t)HC * N;

    k_hist<<<2 * HR * HC, 256, 0, stream>>>(eidx, partials, N, E, HR);
    int nb = (N + 1023) / 1024;
    k_rs<<<nb, 1024, 0, stream>>>(partials, dis, dsi, cnt, rowptr, bsum, N);
    k_scan3<<<nb, 1024, 0, stream>>>(cnt, bsum, rowptr, pdst, cbase, N, nb);

    int SB = SR * HC;
    int packn = (N + 1) * 32 + K * 4096 + 4096;
    int pblk = (packn + 255) / 256;
    k_scpk<<<SB + pblk, 256, 0, stream>>>(src, dst, cbase, srcs, N, E, SB,
                                          x, dis, W, Ysb, Wt, Walt, K, PSE);

    // prop grid: 8 nodes per wave
    int waves = (N + 7) / 8;
    int pblocks = (waves * 64 + 255) / 256;
    for (int p = 1; p < K; ++p) {
        float scale = (p == 1) ? 1.f : 2.f;
        float beta  = (p == 1) ? 0.f : -1.f;
        const unsigned short* Ysin = Ysb + (size_t)(p - 1) * PSE;
        const unsigned short* Ysm2 = Ysb + (size_t)(p >= 2 ? p - 2 : 0) * PSE;
        k_prop<<<pblocks, 256, 0, stream>>>(
            Ysin, Ysm2, Ysb + (size_t)p * PSE,
            rowptr, srcs, dis, N, E, scale, beta);
    }

    if (K == 8)      k_gemm<16><<<512, 256, 0, stream>>>(Ysb, Wt, bias, dsi, x, Walt, out, N, PSE);
    else if (K == 4) k_gemm<8><<<512, 256, 0, stream>>>(Ysb, Wt, bias, dsi, x, Walt, out, N, PSE);
    else if (K == 2) k_gemm<4><<<512, 256, 0, stream>>>(Ysb, Wt, bias, dsi, x, Walt, out, N, PSE);
    else if (K == 1) k_gemm<2><<<512, 256, 0, stream>>>(Ysb, Wt, bias, dsi, x, Walt, out, N, PSE);
}